// Round 4
// baseline (203.839 us; speedup 1.0000x reference)
//
#include <hip/hip_runtime.h>

typedef unsigned short u16;
typedef unsigned int u32;
typedef __bf16 bf16x8 __attribute__((ext_vector_type(8)));
typedef float f32x4 __attribute__((ext_vector_type(4)));
typedef unsigned short u16x8 __attribute__((ext_vector_type(8)));
typedef unsigned short u16x4 __attribute__((ext_vector_type(4)));

__device__ __forceinline__ float bf2f(u16 u) {
    union { unsigned int i; float f; } c; c.i = ((unsigned int)u) << 16; return c.f;
}
__device__ __forceinline__ u16 f2bf(float f) {
    union { float f; unsigned int i; } c; c.f = f;
    unsigned int r = c.i + 0x7FFFu + ((c.i >> 16) & 1u);  // RNE
    return (u16)(r >> 16);
}
__device__ __forceinline__ u16 f2bf_rtz(float f) {   // truncate: 1 VALU op
    union { float f; unsigned int i; } c; c.f = f;
    return (u16)(c.i >> 16);
}
__device__ __forceinline__ float fast_exp2(float x) {
#if __has_builtin(__builtin_amdgcn_exp2f)
    return __builtin_amdgcn_exp2f(x);   // raw v_exp_f32, no OCML fixup
#else
    return exp2f(x);
#endif
}
__device__ __forceinline__ bf16x8 u2b(u16x8 v) {
    return __builtin_bit_cast(bf16x8, v);
}
// async global->LDS, 16B/lane; LDS dest = wave-uniform base + lane*16
__device__ __forceinline__ void async16(const void* g, void* l) {
    __builtin_amdgcn_global_load_lds(
        (const __attribute__((address_space(1))) u32*)g,
        (__attribute__((address_space(3))) u32*)l, 16, 0, 0);
}

// ---------------------------------------------------------------------------
// Merged prepass (one launch) — measured win (R11/R12):
//  blocks [0,2048):    x f32 -> bf16 Xb (8 elems/thread)
//  blocks [2048,5120): transpose+cast qkv_w [1024][3072] -> qwT [3072][1024]
//  blocks [5120,6144): transpose+cast proj_w [1024][1024] -> pwT [1024][1024]
// ---------------------------------------------------------------------------
__global__ __launch_bounds__(256) void prep(
    const float* __restrict__ X, u16* __restrict__ Xb,
    const float* __restrict__ qkv_w, u16* __restrict__ qwT,
    const float* __restrict__ proj_w, u16* __restrict__ pwT)
{
    __shared__ float tile[32][33];
    const int blk = blockIdx.x;
    const int t = threadIdx.x;
    if (blk < 2048) {
        const size_t i = ((size_t)blk * 256 + t) * 8;
        u16x8 h;
        #pragma unroll
        for (int e = 0; e < 8; ++e) h[e] = f2bf(X[i + e]);
        *(u16x8*)&Xb[i] = h;
        return;
    }
    const float* W; u16* Th; int K, N, bx, by;
    if (blk < 5120) {
        W = qkv_w; Th = qwT; K = 1024; N = 3072;
        bx = (blk - 2048) % 96; by = (blk - 2048) / 96;
    } else {
        W = proj_w; Th = pwT; K = 1024; N = 1024;
        bx = (blk - 5120) % 32; by = (blk - 5120) / 32;
    }
    const int bk = by * 32, bn = bx * 32;
    const int tx = t & 31, ty = t >> 5;  // 32 x 8
    #pragma unroll
    for (int r = ty; r < 32; r += 8)
        tile[r][tx] = W[(size_t)(bk + r) * N + bn + tx];
    __syncthreads();
    #pragma unroll
    for (int r = ty; r < 32; r += 8)
        Th[(size_t)(bn + r) * K + bk + tx] = f2bf(tile[tx][r]);
}

// ---------------------------------------------------------------------------
// QKV GEMM (128x128 tile, BK=32) with fused bias + per-head RMSNorm ->
// Qb/Kb bf16 [bh][n][64] (q gets 1/8*log2e folded in) and V transpose ->
// Vt bf16 [bh][d][n] with key-slot permutation (see flash).
// R4: flash-style double-buffered staging — DMA for k+1 issued right after
// the single per-iter barrier, so L2 latency hides under the 16 MFMA of
// tile k (was: issue+drain inside the same interval = exposed every iter).
// C/D layout: col = lane&15, row = (lane>>4)*4 + reg (verified m89/m91).
// ---------------------------------------------------------------------------
__global__ __launch_bounds__(256) void gemm_qkv(
    const u16* __restrict__ AH, const u16* __restrict__ BH,
    const float* __restrict__ bias,
    u16* __restrict__ Qb, u16* __restrict__ Kb, u16* __restrict__ Vt,
    const float* __restrict__ qw, const float* __restrict__ kw)
{
    const int K = 1024;
    __shared__ __align__(16) u16 AhT[2 * 128 * 32];
    __shared__ __align__(16) u16 BhT[2 * 128 * 32];
    const int t = threadIdx.x;
    const int bm = blockIdx.y * 128, bn = blockIdx.x * 128;
    const int wave = t >> 6, lane = t & 63;
    const int wm = (wave >> 1) * 64, wn = (wave & 1) * 64;
    const int l15 = lane & 15, quad = lane >> 4;
    const int srow = lane >> 2, scol = (lane & 3) * 8;

    f32x4 acc[4][4];
    const f32x4 zero = {0.0f, 0.0f, 0.0f, 0.0f};
    #pragma unroll
    for (int i = 0; i < 4; ++i)
        #pragma unroll
        for (int j = 0; j < 4; ++j) acc[i][j] = zero;

    // prologue: stage k0=0 into buffer 0
    #pragma unroll
    for (int rr = 0; rr < 2; ++rr) {
        const int r0 = (rr * 4 + wave) * 16;
        async16(&AH[(size_t)(bm + r0 + srow) * K + scol], &AhT[r0 * 32]);
        async16(&BH[(size_t)(bn + r0 + srow) * K + scol], &BhT[r0 * 32]);
    }

    int cur = 0;
    for (int k0 = 0; k0 < K; k0 += 32) {
        // single barrier: drains DMA for buf[cur] (issued last iter) and
        // fences prior-iter reads of buf[cur^1] before its DMA below.
        __syncthreads();
        if (k0 + 32 < K) {
            const int nb = (cur ^ 1) * 4096;
            #pragma unroll
            for (int rr = 0; rr < 2; ++rr) {
                const int r0 = (rr * 4 + wave) * 16;
                async16(&AH[(size_t)(bm + r0 + srow) * K + k0 + 32 + scol],
                        &AhT[nb + r0 * 32]);
                async16(&BH[(size_t)(bn + r0 + srow) * K + k0 + 32 + scol],
                        &BhT[nb + r0 * 32]);
            }
        }
        const int cb = cur * 4096;
        bf16x8 ah[4], bh[4];
        #pragma unroll
        for (int i = 0; i < 4; ++i)
            ah[i] = *(const bf16x8*)&AhT[cb + (wm + i * 16 + l15) * 32 + quad * 8];
        #pragma unroll
        for (int j = 0; j < 4; ++j)
            bh[j] = *(const bf16x8*)&BhT[cb + (wn + j * 16 + l15) * 32 + quad * 8];
        #pragma unroll
        for (int i = 0; i < 4; ++i)
            #pragma unroll
            for (int j = 0; j < 4; ++j)
                acc[i][j] = __builtin_amdgcn_mfma_f32_16x16x32_bf16(
                    ah[i], bh[j], acc[i][j], 0, 0, 0);
        cur ^= 1;
    }

    // wave's 64-col group = one (section, head) pair
    const int gc0 = bn + wn;
    const int sec = gc0 >> 10;              // 0=q, 1=k, 2=v
    const int h = (gc0 & 1023) >> 6;
    const int b = bm >> 11;
    const int bhd = b * 16 + h;
    float bv[4], wj[4];
    #pragma unroll
    for (int j = 0; j < 4; ++j) {
        const int d = j * 16 + l15;
        bv[j] = bias[gc0 + d];
        wj[j] = (sec == 2) ? 0.0f : (sec ? kw[d] : qw[d] * 0.18033688011f);
    }
    if (sec < 2) {
        u16* dst = sec ? Kb : Qb;
        #pragma unroll
        for (int i = 0; i < 4; ++i) {
            float val[4][4];
            float ss[4] = {0.0f, 0.0f, 0.0f, 0.0f};
            #pragma unroll
            for (int j = 0; j < 4; ++j)
                #pragma unroll
                for (int r = 0; r < 4; ++r) {
                    val[j][r] = acc[i][j][r] + bv[j];
                    ss[r] += val[j][r] * val[j][r];
                }
            #pragma unroll
            for (int r = 0; r < 4; ++r) {
                #pragma unroll
                for (int m = 1; m < 16; m <<= 1)
                    ss[r] += __shfl_xor(ss[r], m, 64);
                const float nrm = rsqrtf(ss[r] * 0.015625f + 1e-6f);
                const int n = (bm + wm + i * 16 + quad * 4 + r) & 2047;
                const size_t rowb = ((size_t)bhd * 2048 + n) * 64;
                #pragma unroll
                for (int j = 0; j < 4; ++j)
                    dst[rowb + j * 16 + l15] = f2bf(val[j][r] * nrm * wj[j]);
            }
        }
    } else {
        const int nb = (bm + wm) & 2047;        // 64-aligned tile base
        #pragma unroll
        for (int i = 0; i < 4; ++i) {
            // slot permutation: key 16*i+4*quad+r -> (i&1)*32+8*quad+(i>>1)*4+r
            const int s0 = (i & 1) * 32 + quad * 8 + (i >> 1) * 4;
            #pragma unroll
            for (int j = 0; j < 4; ++j) {
                const int d = j * 16 + l15;
                u16x4 pk;
                #pragma unroll
                for (int r = 0; r < 4; ++r)
                    pk[r] = f2bf(acc[i][j][r] + bv[j]);
                *(u16x4*)&Vt[((size_t)bhd * 64 + d) * 2048 + nb + s0] = pk;
            }
        }
    }
}

// ---------------------------------------------------------------------------
// Proj GEMM, 64x128 tile. R4: same dbuf single-barrier staging as gemm_qkv.
// out f32 = Attn @ pwT^T + bias.
// ---------------------------------------------------------------------------
__global__ __launch_bounds__(256) void gemm_proj(
    const u16* __restrict__ AH, const u16* __restrict__ BH,
    const float* __restrict__ bias, float* __restrict__ C)
{
    const int N = 1024, K = 1024;
    __shared__ __align__(16) u16 AhT[2 * 64 * 32];
    __shared__ __align__(16) u16 BhT[2 * 128 * 32];
    const int t = threadIdx.x;
    const int bm = blockIdx.y * 64, bn = blockIdx.x * 128;
    const int wave = t >> 6, lane = t & 63;
    const int l15 = lane & 15, quad = lane >> 4;
    const int srow = lane >> 2, scol = (lane & 3) * 8;

    f32x4 acc[4][2];
    const f32x4 zero = {0.0f, 0.0f, 0.0f, 0.0f};
    #pragma unroll
    for (int i = 0; i < 4; ++i)
        #pragma unroll
        for (int j = 0; j < 2; ++j) acc[i][j] = zero;

    // prologue: stage k0=0 into buffer 0
    {
        const int r0 = wave * 16;
        async16(&AH[(size_t)(bm + r0 + srow) * K + scol], &AhT[r0 * 32]);
    }
    #pragma unroll
    for (int cc = 0; cc < 2; ++cc) {
        const int r0 = (wave * 2 + cc) * 16;
        async16(&BH[(size_t)(bn + r0 + srow) * K + scol], &BhT[r0 * 32]);
    }

    int cur = 0;
    for (int k0 = 0; k0 < K; k0 += 32) {
        __syncthreads();
        if (k0 + 32 < K) {
            const int nbA = (cur ^ 1) * 2048, nbB = (cur ^ 1) * 4096;
            {
                const int r0 = wave * 16;
                async16(&AH[(size_t)(bm + r0 + srow) * K + k0 + 32 + scol],
                        &AhT[nbA + r0 * 32]);
            }
            #pragma unroll
            for (int cc = 0; cc < 2; ++cc) {
                const int r0 = (wave * 2 + cc) * 16;
                async16(&BH[(size_t)(bn + r0 + srow) * K + k0 + 32 + scol],
                        &BhT[nbB + r0 * 32]);
            }
        }
        const int cbA = cur * 2048, cbB = cur * 4096;
        bf16x8 ah[4], bh[2];
        #pragma unroll
        for (int i = 0; i < 4; ++i)
            ah[i] = *(const bf16x8*)&AhT[cbA + (i * 16 + l15) * 32 + quad * 8];
        #pragma unroll
        for (int j = 0; j < 2; ++j)
            bh[j] = *(const bf16x8*)
                &BhT[cbB + (wave * 32 + j * 16 + l15) * 32 + quad * 8];
        #pragma unroll
        for (int i = 0; i < 4; ++i)
            #pragma unroll
            for (int j = 0; j < 2; ++j)
                acc[i][j] = __builtin_amdgcn_mfma_f32_16x16x32_bf16(
                    ah[i], bh[j], acc[i][j], 0, 0, 0);
        cur ^= 1;
    }

    #pragma unroll
    for (int j = 0; j < 2; ++j) {
        const int col = bn + wave * 32 + j * 16 + l15;
        const float bv = bias[col];
        #pragma unroll
        for (int i = 0; i < 4; ++i) {
            const int row = bm + i * 16 + quad * 4;
            #pragma unroll
            for (int r = 0; r < 4; ++r)
                C[(size_t)(row + r) * N + col] = acc[i][j][r] + bv;
        }
    }
}

// ---------------------------------------------------------------------------
// MFMA flash attention v11 = v8 geometry (best measured: 4 waves, 128-row Q
// tile, grid 512) + KVBLK=128 (R3 post-mortem: per-iteration fixed cost —
// barrier + drain + chain re-ramp ~1.9K cyc — dominates; halve the count).
// Per barrier interval: stage two 64-key half-tiles (16KB K + 16KB V), run
// the verified v8 body per half. 16 iters instead of 32; 2 independent
// S-chains per interval for ILP. LDS 64KB dbuf -> 2 blocks/CU (same as v8).
//  * In-reg P: slot = (nt&1)*32 + 8*quad + (nt>>1)*4 + r within each 64-key
//    half, Vt stored permuted to match (gemm_qkv); zero cross-lane traffic.
//  * Row-sum via ones-MFMA into osum; epilogue needs no shfl/LDS.
// Grid 1-D 512; bh = bid & 31 keeps a head's q-tiles on one XCD.
// ---------------------------------------------------------------------------
__global__ __launch_bounds__(256) void flash_attn_mfma(
    const u16* __restrict__ Qb, const u16* __restrict__ Kb,
    const u16* __restrict__ Vt, u16* __restrict__ Attn)
{
    __shared__ __align__(16) u16 Klds[2 * 2 * 64 * 64];  // [dbuf][half][key][d]
    __shared__ __align__(16) u16 Vlds[2 * 2 * 64 * 64];  // [dbuf][half][d][slot]

    const int t = threadIdx.x;
    const int bid = blockIdx.x;
    const int bh = bid & 31;       // low bits -> same XCD for all qt of a head
    const int qt = bid >> 5;       // 0..15
    const int n0 = qt * 128;
    const size_t kbase = (size_t)bh * 2048 * 64;
    const size_t vbase = (size_t)bh * 64 * 2048;
    const int wave = t >> 6, lane = t & 63;
    const int l15 = lane & 15, quad = lane >> 4;
    const int srow8 = lane >> 3;
    const int sgrp = lane & 7;

    // Q frags direct from global (B-operand: col=q, k=d); loaded once.
    bf16x8 qf[2][2];
    #pragma unroll
    for (int qs = 0; qs < 2; ++qs) {
        const size_t qrow =
            ((size_t)bh * 2048 + n0 + wave * 32 + qs * 16 + l15) * 64;
        qf[qs][0] = *(const bf16x8*)&Qb[qrow + quad * 8];
        qf[qs][1] = *(const bf16x8*)&Qb[qrow + 32 + quad * 8];
    }

    int kofs[4][2];
    #pragma unroll
    for (int nt = 0; nt < 4; ++nt) {
        const int row = nt * 16 + l15;
        kofs[nt][0] = row * 64 + ((quad ^ (row & 7)) * 8);
        kofs[nt][1] = row * 64 + (((quad + 4) ^ (row & 7)) * 8);
    }

    f32x4 o[2][4];
    const f32x4 zero = {0.0f, 0.0f, 0.0f, 0.0f};
    #pragma unroll
    for (int qs = 0; qs < 2; ++qs)
        #pragma unroll
        for (int dt = 0; dt < 4; ++dt) o[qs][dt] = zero;
    f32x4 osum[2] = {zero, zero};
    bf16x8 ones;
    #pragma unroll
    for (int e = 0; e < 8; ++e) ones[e] = (__bf16)1.0f;

    // prologue: stage K/V tile 0 (both halves) into buffer 0
    #pragma unroll
    for (int h = 0; h < 2; ++h)
        #pragma unroll
        for (int cc = 0; cc < 2; ++cc) {
            const int r0 = (wave + cc * 4) * 8;
            const int row = r0 + srow8;
            const int gg = sgrp ^ (row & 7);
            async16(&Kb[kbase + (size_t)(h * 64 + row) * 64 + gg * 8],
                    &Klds[h * 4096 + r0 * 64]);
            async16(&Vt[vbase + (size_t)row * 2048 + h * 64 + gg * 8],
                    &Vlds[h * 4096 + r0 * 64]);
        }

    for (int kt = 0; kt < 16; ++kt) {
        // Single barrier: drains the DMA for buf[kt&1] (issued one full
        // iteration ago) and fences prior-iter reads of buf[(kt+1)&1].
        __syncthreads();
        if (kt + 1 < 16) {   // prefetch next 128-key tile into other buffer
            const int nb = ((kt + 1) & 1) * 8192;
            #pragma unroll
            for (int h = 0; h < 2; ++h)
                #pragma unroll
                for (int cc = 0; cc < 2; ++cc) {
                    const int r0 = (wave + cc * 4) * 8;
                    const int row = r0 + srow8;
                    const int gg = sgrp ^ (row & 7);
                    async16(&Kb[kbase +
                                (size_t)((kt + 1) * 128 + h * 64 + row) * 64 +
                                gg * 8],
                            &Klds[nb + h * 4096 + r0 * 64]);
                    async16(&Vt[vbase + (size_t)row * 2048 +
                                (kt + 1) * 128 + h * 64 + gg * 8],
                            &Vlds[nb + h * 4096 + r0 * 64]);
                }
        }
        const int cb = (kt & 1) * 8192;

        #pragma unroll
        for (int h = 0; h < 2; ++h) {
            const int hb = cb + h * 4096;

            // S^T = K Q^T : s[qs][nt][r] = S[key=16nt+4quad+r][q=l15]
            f32x4 s[2][4];
            #pragma unroll
            for (int nt = 0; nt < 4; ++nt) {
                bf16x8 kf0 = *(const bf16x8*)&Klds[hb + kofs[nt][0]];
                bf16x8 kf1 = *(const bf16x8*)&Klds[hb + kofs[nt][1]];
                __builtin_amdgcn_s_setprio(1);
                #pragma unroll
                for (int qs = 0; qs < 2; ++qs) {
                    s[qs][nt] = __builtin_amdgcn_mfma_f32_16x16x32_bf16(
                        kf0, qf[qs][0], zero, 0, 0, 0);
                    s[qs][nt] = __builtin_amdgcn_mfma_f32_16x16x32_bf16(
                        kf1, qf[qs][1], s[qs][nt], 0, 0, 0);
                }
                __builtin_amdgcn_s_setprio(0);
            }

            // p = exp2(s); pack IN-REGISTER into A-fragments.
            // pf[qs][m] slots quad*8+j: j=0..3 <- s[qs][m][j],
            // j=4..7 <- s[qs][m+2][j-4] — matches the Vt slot permutation.
            bf16x8 pf[2][2];
            #pragma unroll
            for (int qs = 0; qs < 2; ++qs) {
                #pragma unroll
                for (int m = 0; m < 2; ++m) {
                    u16x8 pk;
                    #pragma unroll
                    for (int r = 0; r < 4; ++r) {
                        pk[r]     = f2bf_rtz(fast_exp2(s[qs][m][r]));
                        pk[4 + r] = f2bf_rtz(fast_exp2(s[qs][m + 2][r]));
                    }
                    pf[qs][m] = u2b(pk);
                }
            }

            // O += P V ; row-sum via ones-MFMA
            #pragma unroll
            for (int dt = 0; dt < 4; ++dt) {
                bf16x8 vf0 = *(const bf16x8*)&Vlds[hb + kofs[dt][0]];
                bf16x8 vf1 = *(const bf16x8*)&Vlds[hb + kofs[dt][1]];
                __builtin_amdgcn_s_setprio(1);
                #pragma unroll
                for (int qs = 0; qs < 2; ++qs) {
                    o[qs][dt] = __builtin_amdgcn_mfma_f32_16x16x32_bf16(
                        pf[qs][0], vf0, o[qs][dt], 0, 0, 0);
                    o[qs][dt] = __builtin_amdgcn_mfma_f32_16x16x32_bf16(
                        pf[qs][1], vf1, o[qs][dt], 0, 0, 0);
                }
                __builtin_amdgcn_s_setprio(0);
            }
            __builtin_amdgcn_s_setprio(1);
            #pragma unroll
            for (int qs = 0; qs < 2; ++qs) {
                osum[qs] = __builtin_amdgcn_mfma_f32_16x16x32_bf16(
                    pf[qs][0], ones, osum[qs], 0, 0, 0);
                osum[qs] = __builtin_amdgcn_mfma_f32_16x16x32_bf16(
                    pf[qs][1], ones, osum[qs], 0, 0, 0);
            }
            __builtin_amdgcn_s_setprio(0);
        }
    }

    // osum[qs][r] on lane(l15,quad) = sum_k P[q=quad*4+r][k], replicated
    // over l15 — exactly the epilogue row indexing. No shfl/LDS needed.
    const size_t obase =
        ((size_t)(bh >> 4) * 2048 + n0) * 1024 + (bh & 15) * 64;
    #pragma unroll
    for (int qs = 0; qs < 2; ++qs)
        #pragma unroll
        for (int r = 0; r < 4; ++r) {
            const float inv = 1.0f / osum[qs][r];
            const size_t rbase =
                obase + (size_t)(wave * 32 + qs * 16 + quad * 4 + r) * 1024;
            #pragma unroll
            for (int dt = 0; dt < 4; ++dt)
                Attn[rbase + dt * 16 + l15] = f2bf(o[qs][dt][r] * inv);
        }
}

// ---------------------------------------------------------------------------
extern "C" void kernel_launch(void* const* d_in, const int* in_sizes, int n_in,
                              void* d_out, int out_size, void* d_ws, size_t ws_size,
                              hipStream_t stream)
{
    const float* x      = (const float*)d_in[0];  // [2,2048,1024] f32
    const float* qkv_w  = (const float*)d_in[1];  // [1024,3072]
    const float* qkv_b  = (const float*)d_in[2];  // [3072]
    const float* q_nw   = (const float*)d_in[3];  // [64]
    const float* k_nw   = (const float*)d_in[4];  // [64]
    const float* proj_w = (const float*)d_in[5];  // [1024,1024]
    const float* proj_b = (const float*)d_in[6];  // [1024]
    float* out = (float*)d_out;                   // [2,2048,1024] f32

    // ws layout (48 MB):
    //  [0,8M)    Attn bf16
    //  [8,14M)   qwT bf16     [14,16M) pwT bf16
    //  [16,24M)  Xb bf16
    //  [24,32M)  Qb bf16      [32,40M) Kb bf16   [40,48M) Vt bf16
    char* ws = (char*)d_ws;
    u16* AttnB = (u16*)ws;
    u16* qwT   = (u16*)(ws + 8388608);
    u16* pwT   = (u16*)(ws + 14680064);
    u16* Xb    = (u16*)(ws + 16777216);
    u16* QbB   = (u16*)(ws + 25165824);
    u16* KbB   = (u16*)(ws + 33554432);
    u16* VtB   = (u16*)(ws + 41943040);
    (void)in_sizes; (void)n_in; (void)out_size;
    // Diagnostic guard: if ws too small, emit nothing -> absmax == max|ref|.
    if (ws_size < 50331648u) return;

    // merged prepass: cast x + transpose both weights (one launch)
    prep<<<dim3(6144), 256, 0, stream>>>(x, Xb, qkv_w, qwT, proj_w, pwT);
    // QKV GEMM (dbuf staging) with fused bias + RMSNorm + head-split epilogue
    gemm_qkv<<<dim3(3072 / 128, 4096 / 128), 256, 0, stream>>>(
        Xb, qwT, qkv_b, QbB, KbB, VtB, q_nw, k_nw);
    // flash attention v11: v8 geometry, KVBLK=128, 16 barrier intervals
    flash_attn_mfma<<<dim3(512), 256, 0, stream>>>(QbB, KbB, VtB, AttnB);
    // out = attn @ proj_w + proj_b (f32), dbuf staging
    gemm_proj<<<dim3(1024 / 128, 4096 / 64), 256, 0, stream>>>(
        AttnB, pwT, proj_b, out);
}

// Round 5
// 198.706 us; speedup vs baseline: 1.0258x; 1.0258x over previous
//
#include <hip/hip_runtime.h>

typedef unsigned short u16;
typedef unsigned int u32;
typedef __bf16 bf16x8 __attribute__((ext_vector_type(8)));
typedef float f32x4 __attribute__((ext_vector_type(4)));
typedef unsigned short u16x8 __attribute__((ext_vector_type(8)));
typedef unsigned short u16x4 __attribute__((ext_vector_type(4)));

__device__ __forceinline__ float bf2f(u16 u) {
    union { unsigned int i; float f; } c; c.i = ((unsigned int)u) << 16; return c.f;
}
__device__ __forceinline__ u16 f2bf(float f) {
    union { float f; unsigned int i; } c; c.f = f;
    unsigned int r = c.i + 0x7FFFu + ((c.i >> 16) & 1u);  // RNE
    return (u16)(r >> 16);
}
__device__ __forceinline__ u16 f2bf_rtz(float f) {   // truncate: 1 VALU op
    union { float f; unsigned int i; } c; c.f = f;
    return (u16)(c.i >> 16);
}
__device__ __forceinline__ float fast_exp2(float x) {
#if __has_builtin(__builtin_amdgcn_exp2f)
    return __builtin_amdgcn_exp2f(x);   // raw v_exp_f32, no OCML fixup
#else
    return exp2f(x);
#endif
}
__device__ __forceinline__ bf16x8 u2b(u16x8 v) {
    return __builtin_bit_cast(bf16x8, v);
}
// async global->LDS, 16B/lane; LDS dest = wave-uniform base + lane*16
__device__ __forceinline__ void async16(const void* g, void* l) {
    __builtin_amdgcn_global_load_lds(
        (const __attribute__((address_space(1))) u32*)g,
        (__attribute__((address_space(3))) u32*)l, 16, 0, 0);
}

// ---------------------------------------------------------------------------
// Merged prepass (one launch) — measured win (R11/R12):
//  blocks [0,2048):    x f32 -> bf16 Xb (8 elems/thread)
//  blocks [2048,5120): transpose+cast qkv_w [1024][3072] -> qwT [3072][1024]
//  blocks [5120,6144): transpose+cast proj_w [1024][1024] -> pwT [1024][1024]
// ---------------------------------------------------------------------------
__global__ __launch_bounds__(256) void prep(
    const float* __restrict__ X, u16* __restrict__ Xb,
    const float* __restrict__ qkv_w, u16* __restrict__ qwT,
    const float* __restrict__ proj_w, u16* __restrict__ pwT)
{
    __shared__ float tile[32][33];
    const int blk = blockIdx.x;
    const int t = threadIdx.x;
    if (blk < 2048) {
        const size_t i = ((size_t)blk * 256 + t) * 8;
        u16x8 h;
        #pragma unroll
        for (int e = 0; e < 8; ++e) h[e] = f2bf(X[i + e]);
        *(u16x8*)&Xb[i] = h;
        return;
    }
    const float* W; u16* Th; int K, N, bx, by;
    if (blk < 5120) {
        W = qkv_w; Th = qwT; K = 1024; N = 3072;
        bx = (blk - 2048) % 96; by = (blk - 2048) / 96;
    } else {
        W = proj_w; Th = pwT; K = 1024; N = 1024;
        bx = (blk - 5120) % 32; by = (blk - 5120) / 32;
    }
    const int bk = by * 32, bn = bx * 32;
    const int tx = t & 31, ty = t >> 5;  // 32 x 8
    #pragma unroll
    for (int r = ty; r < 32; r += 8)
        tile[r][tx] = W[(size_t)(bk + r) * N + bn + tx];
    __syncthreads();
    #pragma unroll
    for (int r = ty; r < 32; r += 8)
        Th[(size_t)(bn + r) * K + bk + tx] = f2bf(tile[tx][r]);
}

// ---------------------------------------------------------------------------
// QKV GEMM (128x128 tile, BK=32, R1 two-barrier staging — dbuf measured
// slower in R4) with fused bias + per-head RMSNorm -> Qb/Kb bf16 [bh][n][64]
// (q gets 1/8*log2e folded in) and V transpose -> Vt bf16 [bh][d][n] with
// key-slot permutation (see flash).
// R5: LDS XOR-swizzle kills the measured 3.1M bank-conflict cycles (m98's
// known conflict: [*][32]-u16 tile, 64B rows -> 16-lane groups hit 2/8
// bank-quads). slot' = quad ^ ((row>>1)&3); since global_load_lds writes
// linearly, the inverse perm goes on the staging lane's GLOBAL column
// (both-sides-or-neither). After: bank-quad = 4*(l15&1) + (quad^((l15>>1)&3))
// covers all 8 quads 2x per 16-lane group -> 2-way = free.
// C/D layout: col = lane&15, row = (lane>>4)*4 + reg (verified m89/m91).
// ---------------------------------------------------------------------------
__global__ __launch_bounds__(256) void gemm_qkv(
    const u16* __restrict__ AH, const u16* __restrict__ BH,
    const float* __restrict__ bias,
    u16* __restrict__ Qb, u16* __restrict__ Kb, u16* __restrict__ Vt,
    const float* __restrict__ qw, const float* __restrict__ kw)
{
    const int K = 1024;
    __shared__ __align__(16) u16 AhT[128 * 32];
    __shared__ __align__(16) u16 BhT[128 * 32];
    const int t = threadIdx.x;
    const int bm = blockIdx.y * 128, bn = blockIdx.x * 128;
    const int wave = t >> 6, lane = t & 63;
    const int wm = (wave >> 1) * 64, wn = (wave & 1) * 64;
    const int l15 = lane & 15, quad = lane >> 4;
    // staging: 16B/lane; row = r0 + (lane>>2); global col chunk carries the
    // inverse swizzle g(row) = (row>>1)&3 = (lane>>3)&3  (r0 multiple of 16)
    const int srow = lane >> 2;
    const int scol = (((lane & 3) ^ ((lane >> 3) & 3))) * 8;
    // fragment-read swizzle: slot = quad ^ ((row>>1)&3), row = ..16*i + l15
    const int rq = (quad ^ ((l15 >> 1) & 3)) * 8;

    f32x4 acc[4][4];
    const f32x4 zero = {0.0f, 0.0f, 0.0f, 0.0f};
    #pragma unroll
    for (int i = 0; i < 4; ++i)
        #pragma unroll
        for (int j = 0; j < 4; ++j) acc[i][j] = zero;

    for (int k0 = 0; k0 < K; k0 += 32) {
        #pragma unroll
        for (int rr = 0; rr < 2; ++rr) {
            const int r0 = (rr * 4 + wave) * 16;
            const size_t ga = (size_t)(bm + r0 + srow) * K + k0 + scol;
            const size_t gb = (size_t)(bn + r0 + srow) * K + k0 + scol;
            async16(&AH[ga], &AhT[r0 * 32]);
            async16(&BH[gb], &BhT[r0 * 32]);
        }
        __syncthreads();
        bf16x8 ah[4], bh[4];
        #pragma unroll
        for (int i = 0; i < 4; ++i)
            ah[i] = *(const bf16x8*)&AhT[(wm + i * 16 + l15) * 32 + rq];
        #pragma unroll
        for (int j = 0; j < 4; ++j)
            bh[j] = *(const bf16x8*)&BhT[(wn + j * 16 + l15) * 32 + rq];
        #pragma unroll
        for (int i = 0; i < 4; ++i)
            #pragma unroll
            for (int j = 0; j < 4; ++j)
                acc[i][j] = __builtin_amdgcn_mfma_f32_16x16x32_bf16(
                    ah[i], bh[j], acc[i][j], 0, 0, 0);
        __syncthreads();
    }

    // wave's 64-col group = one (section, head) pair
    const int gc0 = bn + wn;
    const int sec = gc0 >> 10;              // 0=q, 1=k, 2=v
    const int h = (gc0 & 1023) >> 6;
    const int b = bm >> 11;
    const int bhd = b * 16 + h;
    float bv[4], wj[4];
    #pragma unroll
    for (int j = 0; j < 4; ++j) {
        const int d = j * 16 + l15;
        bv[j] = bias[gc0 + d];
        wj[j] = (sec == 2) ? 0.0f : (sec ? kw[d] : qw[d] * 0.18033688011f);
    }
    if (sec < 2) {
        u16* dst = sec ? Kb : Qb;
        #pragma unroll
        for (int i = 0; i < 4; ++i) {
            float val[4][4];
            float ss[4] = {0.0f, 0.0f, 0.0f, 0.0f};
            #pragma unroll
            for (int j = 0; j < 4; ++j)
                #pragma unroll
                for (int r = 0; r < 4; ++r) {
                    val[j][r] = acc[i][j][r] + bv[j];
                    ss[r] += val[j][r] * val[j][r];
                }
            #pragma unroll
            for (int r = 0; r < 4; ++r) {
                #pragma unroll
                for (int m = 1; m < 16; m <<= 1)
                    ss[r] += __shfl_xor(ss[r], m, 64);
                const float nrm = rsqrtf(ss[r] * 0.015625f + 1e-6f);
                const int n = (bm + wm + i * 16 + quad * 4 + r) & 2047;
                const size_t rowb = ((size_t)bhd * 2048 + n) * 64;
                #pragma unroll
                for (int j = 0; j < 4; ++j)
                    dst[rowb + j * 16 + l15] = f2bf(val[j][r] * nrm * wj[j]);
            }
        }
    } else {
        const int nb = (bm + wm) & 2047;        // 64-aligned tile base
        #pragma unroll
        for (int i = 0; i < 4; ++i) {
            // slot permutation: key 16*i+4*quad+r -> (i&1)*32+8*quad+(i>>1)*4+r
            const int s0 = (i & 1) * 32 + quad * 8 + (i >> 1) * 4;
            #pragma unroll
            for (int j = 0; j < 4; ++j) {
                const int d = j * 16 + l15;
                u16x4 pk;
                #pragma unroll
                for (int r = 0; r < 4; ++r)
                    pk[r] = f2bf(acc[i][j][r] + bv[j]);
                *(u16x4*)&Vt[((size_t)bhd * 64 + d) * 2048 + nb + s0] = pk;
            }
        }
    }
}

// ---------------------------------------------------------------------------
// Proj GEMM, 64x128 tile, R1 two-barrier staging + R5 LDS XOR-swizzle
// (same derivation as gemm_qkv). out f32 = Attn @ pwT^T + bias.
// ---------------------------------------------------------------------------
__global__ __launch_bounds__(256) void gemm_proj(
    const u16* __restrict__ AH, const u16* __restrict__ BH,
    const float* __restrict__ bias, float* __restrict__ C)
{
    const int N = 1024, K = 1024;
    __shared__ __align__(16) u16 AhT[64 * 32];
    __shared__ __align__(16) u16 BhT[128 * 32];
    const int t = threadIdx.x;
    const int bm = blockIdx.y * 64, bn = blockIdx.x * 128;
    const int wave = t >> 6, lane = t & 63;
    const int l15 = lane & 15, quad = lane >> 4;
    const int srow = lane >> 2;
    const int scol = (((lane & 3) ^ ((lane >> 3) & 3))) * 8;
    const int rq = (quad ^ ((l15 >> 1) & 3)) * 8;

    f32x4 acc[4][2];
    const f32x4 zero = {0.0f, 0.0f, 0.0f, 0.0f};
    #pragma unroll
    for (int i = 0; i < 4; ++i)
        #pragma unroll
        for (int j = 0; j < 2; ++j) acc[i][j] = zero;

    for (int k0 = 0; k0 < K; k0 += 32) {
        {
            const int r0 = wave * 16;
            async16(&AH[(size_t)(bm + r0 + srow) * K + k0 + scol],
                    &AhT[r0 * 32]);
        }
        #pragma unroll
        for (int cc = 0; cc < 2; ++cc) {
            const int r0 = (wave * 2 + cc) * 16;
            async16(&BH[(size_t)(bn + r0 + srow) * K + k0 + scol],
                    &BhT[r0 * 32]);
        }
        __syncthreads();
        bf16x8 ah[4], bh[2];
        #pragma unroll
        for (int i = 0; i < 4; ++i)
            ah[i] = *(const bf16x8*)&AhT[(i * 16 + l15) * 32 + rq];
        #pragma unroll
        for (int j = 0; j < 2; ++j)
            bh[j] = *(const bf16x8*)
                &BhT[(wave * 32 + j * 16 + l15) * 32 + rq];
        #pragma unroll
        for (int i = 0; i < 4; ++i)
            #pragma unroll
            for (int j = 0; j < 2; ++j)
                acc[i][j] = __builtin_amdgcn_mfma_f32_16x16x32_bf16(
                    ah[i], bh[j], acc[i][j], 0, 0, 0);
        __syncthreads();
    }

    #pragma unroll
    for (int j = 0; j < 2; ++j) {
        const int col = bn + wave * 32 + j * 16 + l15;
        const float bv = bias[col];
        #pragma unroll
        for (int i = 0; i < 4; ++i) {
            const int row = bm + i * 16 + quad * 4;
            #pragma unroll
            for (int r = 0; r < 4; ++r)
                C[(size_t)(row + r) * N + col] = acc[i][j][r] + bv;
        }
    }
}

// ---------------------------------------------------------------------------
// MFMA flash attention v12 = v8 geometry (best measured: 4 waves, 128-row
// Q-tile, grid 512, KVBLK=64) + R2's in-reg P + ones-MFMA row-sum.
// R3/R4 refuted: tile-shrink for occupancy (v9/v10) and KVBLK=128 (v11)
// all neutral-to-worse; v8 geometry is the measured optimum of this family.
//  * In-reg P: slot = (nt&1)*32 + 8*quad + (nt>>1)*4 + r, Vt stored
//    permuted to match (gemm_qkv); zero cross-lane traffic, no Plds.
//  * Row-sum via ones-MFMA into osum; epilogue needs no shfl/LDS.
// Grid 1-D 512; bh = bid & 31 keeps a head's 16 q-tiles on one XCD.
// ---------------------------------------------------------------------------
__global__ __launch_bounds__(256) void flash_attn_mfma(
    const u16* __restrict__ Qb, const u16* __restrict__ Kb,
    const u16* __restrict__ Vt, u16* __restrict__ Attn)
{
    __shared__ __align__(16) u16 Klds[2 * 64 * 64];  // swizzled [key][d], dbuf
    __shared__ __align__(16) u16 Vlds[2 * 64 * 64];  // swizzled [d][slot], dbuf

    const int t = threadIdx.x;
    const int bid = blockIdx.x;
    const int bh = bid & 31;       // low bits -> same XCD for all qt of a head
    const int qt = bid >> 5;       // 0..15
    const int n0 = qt * 128;
    const size_t kbase = (size_t)bh * 2048 * 64;
    const size_t vbase = (size_t)bh * 64 * 2048;
    const int wave = t >> 6, lane = t & 63;
    const int l15 = lane & 15, quad = lane >> 4;
    const int srow8 = lane >> 3;
    const int sgrp = lane & 7;

    // Q frags direct from global (B-operand: col=q, k=d); loaded once.
    bf16x8 qf[2][2];
    #pragma unroll
    for (int qs = 0; qs < 2; ++qs) {
        const size_t qrow =
            ((size_t)bh * 2048 + n0 + wave * 32 + qs * 16 + l15) * 64;
        qf[qs][0] = *(const bf16x8*)&Qb[qrow + quad * 8];
        qf[qs][1] = *(const bf16x8*)&Qb[qrow + 32 + quad * 8];
    }

    int kofs[4][2];
    #pragma unroll
    for (int nt = 0; nt < 4; ++nt) {
        const int row = nt * 16 + l15;
        kofs[nt][0] = row * 64 + ((quad ^ (row & 7)) * 8);
        kofs[nt][1] = row * 64 + (((quad + 4) ^ (row & 7)) * 8);
    }

    f32x4 o[2][4];
    const f32x4 zero = {0.0f, 0.0f, 0.0f, 0.0f};
    #pragma unroll
    for (int qs = 0; qs < 2; ++qs)
        #pragma unroll
        for (int dt = 0; dt < 4; ++dt) o[qs][dt] = zero;
    f32x4 osum[2] = {zero, zero};
    bf16x8 ones;
    #pragma unroll
    for (int e = 0; e < 8; ++e) ones[e] = (__bf16)1.0f;

    // prologue: stage K/V tile 0 into buffer 0
    #pragma unroll
    for (int cc = 0; cc < 2; ++cc) {
        const int r0 = (wave + cc * 4) * 8;
        const int row = r0 + srow8;
        const int gg = sgrp ^ (row & 7);
        async16(&Kb[kbase + (size_t)row * 64 + gg * 8], &Klds[r0 * 64]);
        async16(&Vt[vbase + (size_t)row * 2048 + gg * 8], &Vlds[r0 * 64]);
    }

    for (int kt = 0; kt < 32; ++kt) {
        // Single barrier: drains the DMA for buf[kt&1] (issued one full
        // iteration ago) and fences prior-iter reads of buf[(kt+1)&1].
        __syncthreads();
        if (kt + 1 < 32) {   // prefetch next tile into the other buffer
            const int nb = ((kt + 1) & 1) * 4096;
            #pragma unroll
            for (int cc = 0; cc < 2; ++cc) {
                const int r0 = (wave + cc * 4) * 8;
                const int row = r0 + srow8;
                const int gg = sgrp ^ (row & 7);
                async16(&Kb[kbase + (size_t)((kt + 1) * 64 + row) * 64 + gg * 8],
                        &Klds[nb + r0 * 64]);
                async16(&Vt[vbase + (size_t)row * 2048 + (kt + 1) * 64 + gg * 8],
                        &Vlds[nb + r0 * 64]);
            }
        }
        const int cb = (kt & 1) * 4096;

        // S^T = K Q^T : lane gets s[qs][nt][r] = S[key=16nt+4quad+r][q=l15]
        f32x4 s[2][4];
        #pragma unroll
        for (int nt = 0; nt < 4; ++nt) {
            bf16x8 kf0 = *(const bf16x8*)&Klds[cb + kofs[nt][0]];
            bf16x8 kf1 = *(const bf16x8*)&Klds[cb + kofs[nt][1]];
            __builtin_amdgcn_s_setprio(1);
            #pragma unroll
            for (int qs = 0; qs < 2; ++qs) {
                s[qs][nt] = __builtin_amdgcn_mfma_f32_16x16x32_bf16(
                    kf0, qf[qs][0], zero, 0, 0, 0);
                s[qs][nt] = __builtin_amdgcn_mfma_f32_16x16x32_bf16(
                    kf1, qf[qs][1], s[qs][nt], 0, 0, 0);
            }
            __builtin_amdgcn_s_setprio(0);
        }

        // p = exp2(s); pack IN-REGISTER into A-fragments.
        // pf[qs][m] slots quad*8+j: j=0..3 <- s[qs][m][j] (key 16m+4q+j),
        // j=4..7 <- s[qs][m+2][j-4] — matches the Vt slot permutation.
        bf16x8 pf[2][2];
        #pragma unroll
        for (int qs = 0; qs < 2; ++qs) {
            #pragma unroll
            for (int m = 0; m < 2; ++m) {
                u16x8 pk;
                #pragma unroll
                for (int r = 0; r < 4; ++r) {
                    pk[r]     = f2bf_rtz(fast_exp2(s[qs][m][r]));
                    pk[4 + r] = f2bf_rtz(fast_exp2(s[qs][m + 2][r]));
                }
                pf[qs][m] = u2b(pk);
            }
        }

        // O += P V : 2 qsub x 4 d-tiles x 2 ksteps; row-sum via ones-MFMA
        #pragma unroll
        for (int dt = 0; dt < 4; ++dt) {
            bf16x8 vf0 = *(const bf16x8*)&Vlds[cb + kofs[dt][0]];
            bf16x8 vf1 = *(const bf16x8*)&Vlds[cb + kofs[dt][1]];
            __builtin_amdgcn_s_setprio(1);
            #pragma unroll
            for (int qs = 0; qs < 2; ++qs) {
                o[qs][dt] = __builtin_amdgcn_mfma_f32_16x16x32_bf16(
                    pf[qs][0], vf0, o[qs][dt], 0, 0, 0);
                o[qs][dt] = __builtin_amdgcn_mfma_f32_16x16x32_bf16(
                    pf[qs][1], vf1, o[qs][dt], 0, 0, 0);
            }
            __builtin_amdgcn_s_setprio(0);
        }
        __builtin_amdgcn_s_setprio(1);
        #pragma unroll
        for (int qs = 0; qs < 2; ++qs) {
            osum[qs] = __builtin_amdgcn_mfma_f32_16x16x32_bf16(
                pf[qs][0], ones, osum[qs], 0, 0, 0);
            osum[qs] = __builtin_amdgcn_mfma_f32_16x16x32_bf16(
                pf[qs][1], ones, osum[qs], 0, 0, 0);
        }
        __builtin_amdgcn_s_setprio(0);
    }

    // osum[qs][r] on lane(l15,quad) = sum_k P[q=quad*4+r][k], replicated
    // over l15 — exactly the epilogue row indexing. No shfl/LDS needed.
    const size_t obase =
        ((size_t)(bh >> 4) * 2048 + n0) * 1024 + (bh & 15) * 64;
    #pragma unroll
    for (int qs = 0; qs < 2; ++qs)
        #pragma unroll
        for (int r = 0; r < 4; ++r) {
            const float inv = 1.0f / osum[qs][r];
            const size_t rbase =
                obase + (size_t)(wave * 32 + qs * 16 + quad * 4 + r) * 1024;
            #pragma unroll
            for (int dt = 0; dt < 4; ++dt)
                Attn[rbase + dt * 16 + l15] = f2bf(o[qs][dt][r] * inv);
        }
}

// ---------------------------------------------------------------------------
extern "C" void kernel_launch(void* const* d_in, const int* in_sizes, int n_in,
                              void* d_out, int out_size, void* d_ws, size_t ws_size,
                              hipStream_t stream)
{
    const float* x      = (const float*)d_in[0];  // [2,2048,1024] f32
    const float* qkv_w  = (const float*)d_in[1];  // [1024,3072]
    const float* qkv_b  = (const float*)d_in[2];  // [3072]
    const float* q_nw   = (const float*)d_in[3];  // [64]
    const float* k_nw   = (const float*)d_in[4];  // [64]
    const float* proj_w = (const float*)d_in[5];  // [1024,1024]
    const float* proj_b = (const float*)d_in[6];  // [1024]
    float* out = (float*)d_out;                   // [2,2048,1024] f32

    // ws layout (48 MB):
    //  [0,8M)    Attn bf16
    //  [8,14M)   qwT bf16     [14,16M) pwT bf16
    //  [16,24M)  Xb bf16
    //  [24,32M)  Qb bf16      [32,40M) Kb bf16   [40,48M) Vt bf16
    char* ws = (char*)d_ws;
    u16* AttnB = (u16*)ws;
    u16* qwT   = (u16*)(ws + 8388608);
    u16* pwT   = (u16*)(ws + 14680064);
    u16* Xb    = (u16*)(ws + 16777216);
    u16* QbB   = (u16*)(ws + 25165824);
    u16* KbB   = (u16*)(ws + 33554432);
    u16* VtB   = (u16*)(ws + 41943040);
    (void)in_sizes; (void)n_in; (void)out_size;
    // Diagnostic guard: if ws too small, emit nothing -> absmax == max|ref|.
    if (ws_size < 50331648u) return;

    // merged prepass: cast x + transpose both weights (one launch)
    prep<<<dim3(6144), 256, 0, stream>>>(x, Xb, qkv_w, qwT, proj_w, pwT);
    // QKV GEMM (R1 staging + LDS swizzle) with fused bias+RMSNorm epilogue
    gemm_qkv<<<dim3(3072 / 128, 4096 / 128), 256, 0, stream>>>(
        Xb, qwT, qkv_b, QbB, KbB, VtB, q_nw, k_nw);
    // flash attention v12 (v8 geometry + in-reg P + osum)
    flash_attn_mfma<<<dim3(512), 256, 0, stream>>>(QbB, KbB, VtB, AttnB);
    // out = attn @ proj_w + proj_b (f32), R1 staging + LDS swizzle
    gemm_proj<<<dim3(1024 / 128, 4096 / 64), 256, 0, stream>>>(
        AttnB, pwT, proj_b, out);
}

// Round 6
// 198.201 us; speedup vs baseline: 1.0284x; 1.0026x over previous
//
#include <hip/hip_runtime.h>

typedef unsigned short u16;
typedef unsigned int u32;
typedef __bf16 bf16x8 __attribute__((ext_vector_type(8)));
typedef float f32x4 __attribute__((ext_vector_type(4)));
typedef unsigned short u16x8 __attribute__((ext_vector_type(8)));
typedef unsigned short u16x4 __attribute__((ext_vector_type(4)));

__device__ __forceinline__ float bf2f(u16 u) {
    union { unsigned int i; float f; } c; c.i = ((unsigned int)u) << 16; return c.f;
}
__device__ __forceinline__ u16 f2bf(float f) {
    union { float f; unsigned int i; } c; c.f = f;
    unsigned int r = c.i + 0x7FFFu + ((c.i >> 16) & 1u);  // RNE
    return (u16)(r >> 16);
}
__device__ __forceinline__ u16 f2bf_rtz(float f) {   // truncate: 1 VALU op
    union { float f; unsigned int i; } c; c.f = f;
    return (u16)(c.i >> 16);
}
__device__ __forceinline__ float fast_exp2(float x) {
#if __has_builtin(__builtin_amdgcn_exp2f)
    return __builtin_amdgcn_exp2f(x);   // raw v_exp_f32, no OCML fixup
#else
    return exp2f(x);
#endif
}
__device__ __forceinline__ bf16x8 u2b(u16x8 v) {
    return __builtin_bit_cast(bf16x8, v);
}
// async global->LDS, 16B/lane; LDS dest = wave-uniform base + lane*16
__device__ __forceinline__ void async16(const void* g, void* l) {
    __builtin_amdgcn_global_load_lds(
        (const __attribute__((address_space(1))) u32*)g,
        (__attribute__((address_space(3))) u32*)l, 16, 0, 0);
}

// ---------------------------------------------------------------------------
// Merged prepass (one launch) — measured win (R11/R12):
//  blocks [0,2048):    x f32 -> bf16 Xb (8 elems/thread)
//  blocks [2048,5120): transpose+cast qkv_w [1024][3072] -> qwT [3072][1024]
//  blocks [5120,6144): transpose+cast proj_w [1024][1024] -> pwT [1024][1024]
// ---------------------------------------------------------------------------
__global__ __launch_bounds__(256) void prep(
    const float* __restrict__ X, u16* __restrict__ Xb,
    const float* __restrict__ qkv_w, u16* __restrict__ qwT,
    const float* __restrict__ proj_w, u16* __restrict__ pwT)
{
    __shared__ float tile[32][33];
    const int blk = blockIdx.x;
    const int t = threadIdx.x;
    if (blk < 2048) {
        const size_t i = ((size_t)blk * 256 + t) * 8;
        u16x8 h;
        #pragma unroll
        for (int e = 0; e < 8; ++e) h[e] = f2bf(X[i + e]);
        *(u16x8*)&Xb[i] = h;
        return;
    }
    const float* W; u16* Th; int K, N, bx, by;
    if (blk < 5120) {
        W = qkv_w; Th = qwT; K = 1024; N = 3072;
        bx = (blk - 2048) % 96; by = (blk - 2048) / 96;
    } else {
        W = proj_w; Th = pwT; K = 1024; N = 1024;
        bx = (blk - 5120) % 32; by = (blk - 5120) / 32;
    }
    const int bk = by * 32, bn = bx * 32;
    const int tx = t & 31, ty = t >> 5;  // 32 x 8
    #pragma unroll
    for (int r = ty; r < 32; r += 8)
        tile[r][tx] = W[(size_t)(bk + r) * N + bn + tx];
    __syncthreads();
    #pragma unroll
    for (int r = ty; r < 32; r += 8)
        Th[(size_t)(bn + r) * K + bk + tx] = f2bf(tile[tx][r]);
}

// ---------------------------------------------------------------------------
// QKV GEMM — R6: 128x128 tile, BK=64 (32 MFMA/wave per barrier interval,
// 16 intervals instead of 32: the R4 counters showed everything idle —
// MfmaUtil 17 / VALU 11 / HBM 15 / occ 15 — i.e. per-interval DMA-drain
// dominates 16 MFMA of compute; double the compute per drain).
// LDS [128][64] u16 per matrix with 16B-chunk XOR swizzle:
//   LDS chunk' at row holds global chunk  g = chunk' ^ (row&7)
//   staged via inverse perm on the GLOBAL column (linear LDS dest,
//   both-sides-or-neither), read back with the same XOR -> 2-way = free.
// XCD-chunked 1-D grid (T1): xcd = bid&7 owns 3 B-panels (contiguous bn),
// so the 32 blocks sharing a qwT panel hit one L2 (FETCH 40 MB -> ~20).
// Fused bias + per-head RMSNorm -> Qb/Kb bf16 [bh][n][64] (q gets
// 1/8*log2e folded), V transpose -> Vt [bh][d][n] with key-slot perm.
// C/D layout: col = lane&15, row = (lane>>4)*4 + reg (verified m89/m91).
// ---------------------------------------------------------------------------
__global__ __launch_bounds__(256) void gemm_qkv(
    const u16* __restrict__ AH, const u16* __restrict__ BH,
    const float* __restrict__ bias,
    u16* __restrict__ Qb, u16* __restrict__ Kb, u16* __restrict__ Vt,
    const float* __restrict__ qw, const float* __restrict__ kw)
{
    const int K = 1024;
    __shared__ __align__(16) u16 AhT[128 * 64];
    __shared__ __align__(16) u16 BhT[128 * 64];
    const int t = threadIdx.x;
    // XCD-chunked grid: 768 blocks; xcd = bid&7 gets bn panels xcd*3..+2
    const int bid = blockIdx.x;
    const int xcd = bid & 7, slot = bid >> 3;        // slot 0..95
    const int bm = (slot / 3) * 128;                 // 0..31 -> M
    const int bn = (xcd * 3 + (slot % 3)) * 128;     // 0..23 -> N
    const int wave = t >> 6, lane = t & 63;
    const int wm = (wave >> 1) * 64, wn = (wave & 1) * 64;
    const int l15 = lane & 15, quad = lane >> 4;
    // staging: seg = cc*4+wave covers rows seg*8..seg*8+7; lane>>3 = row&7;
    // lane&7 = LDS chunk; global chunk g = (lane&7) ^ (lane>>3)
    const int srow_lo = lane >> 3;
    const int g8 = ((lane & 7) ^ (lane >> 3)) * 8;
    // fragment-read chunk xor: row&7 = l15&7
    const int rx = l15 & 7;

    f32x4 acc[4][4];
    const f32x4 zero = {0.0f, 0.0f, 0.0f, 0.0f};
    #pragma unroll
    for (int i = 0; i < 4; ++i)
        #pragma unroll
        for (int j = 0; j < 4; ++j) acc[i][j] = zero;

    for (int k0 = 0; k0 < K; k0 += 64) {
        #pragma unroll
        for (int cc = 0; cc < 4; ++cc) {
            const int seg = cc * 4 + wave;          // 0..15
            const int row = seg * 8 + srow_lo;      // 0..127
            async16(&AH[(size_t)(bm + row) * K + k0 + g8], &AhT[seg * 512]);
            async16(&BH[(size_t)(bn + row) * K + k0 + g8], &BhT[seg * 512]);
        }
        __syncthreads();
        bf16x8 ah[4][2], bh[4][2];
        #pragma unroll
        for (int i = 0; i < 4; ++i) {
            const int rb = (wm + i * 16 + l15) * 64;
            ah[i][0] = *(const bf16x8*)&AhT[rb + (quad ^ rx) * 8];
            ah[i][1] = *(const bf16x8*)&AhT[rb + (((4 + quad) ^ rx)) * 8];
        }
        #pragma unroll
        for (int j = 0; j < 4; ++j) {
            const int rb = (wn + j * 16 + l15) * 64;
            bh[j][0] = *(const bf16x8*)&BhT[rb + (quad ^ rx) * 8];
            bh[j][1] = *(const bf16x8*)&BhT[rb + (((4 + quad) ^ rx)) * 8];
        }
        #pragma unroll
        for (int i = 0; i < 4; ++i)
            #pragma unroll
            for (int j = 0; j < 4; ++j) {
                acc[i][j] = __builtin_amdgcn_mfma_f32_16x16x32_bf16(
                    ah[i][0], bh[j][0], acc[i][j], 0, 0, 0);
                acc[i][j] = __builtin_amdgcn_mfma_f32_16x16x32_bf16(
                    ah[i][1], bh[j][1], acc[i][j], 0, 0, 0);
            }
        __syncthreads();
    }

    // wave's 64-col group = one (section, head) pair
    const int gc0 = bn + wn;
    const int sec = gc0 >> 10;              // 0=q, 1=k, 2=v
    const int h = (gc0 & 1023) >> 6;
    const int b = bm >> 11;
    const int bhd = b * 16 + h;
    float bv[4], wj[4];
    #pragma unroll
    for (int j = 0; j < 4; ++j) {
        const int d = j * 16 + l15;
        bv[j] = bias[gc0 + d];
        wj[j] = (sec == 2) ? 0.0f : (sec ? kw[d] : qw[d] * 0.18033688011f);
    }
    if (sec < 2) {
        u16* dst = sec ? Kb : Qb;
        #pragma unroll
        for (int i = 0; i < 4; ++i) {
            float val[4][4];
            float ss[4] = {0.0f, 0.0f, 0.0f, 0.0f};
            #pragma unroll
            for (int j = 0; j < 4; ++j)
                #pragma unroll
                for (int r = 0; r < 4; ++r) {
                    val[j][r] = acc[i][j][r] + bv[j];
                    ss[r] += val[j][r] * val[j][r];
                }
            #pragma unroll
            for (int r = 0; r < 4; ++r) {
                #pragma unroll
                for (int m = 1; m < 16; m <<= 1)
                    ss[r] += __shfl_xor(ss[r], m, 64);
                const float nrm = rsqrtf(ss[r] * 0.015625f + 1e-6f);
                const int n = (bm + wm + i * 16 + quad * 4 + r) & 2047;
                const size_t rowb = ((size_t)bhd * 2048 + n) * 64;
                #pragma unroll
                for (int j = 0; j < 4; ++j)
                    dst[rowb + j * 16 + l15] = f2bf(val[j][r] * nrm * wj[j]);
            }
        }
    } else {
        const int nb = (bm + wm) & 2047;        // 64-aligned tile base
        #pragma unroll
        for (int i = 0; i < 4; ++i) {
            // slot permutation: key 16*i+4*quad+r -> (i&1)*32+8*quad+(i>>1)*4+r
            const int s0 = (i & 1) * 32 + quad * 8 + (i >> 1) * 4;
            #pragma unroll
            for (int j = 0; j < 4; ++j) {
                const int d = j * 16 + l15;
                u16x4 pk;
                #pragma unroll
                for (int r = 0; r < 4; ++r)
                    pk[r] = f2bf(acc[i][j][r] + bv[j]);
                *(u16x4*)&Vt[((size_t)bhd * 64 + d) * 2048 + nb + s0] = pk;
            }
        }
    }
}

// ---------------------------------------------------------------------------
// Proj GEMM, 64x128 tile, R1 two-barrier staging + R5 LDS XOR-swizzle
// (same derivation as gemm_qkv R5). out f32 = Attn @ pwT^T + bias.
// ---------------------------------------------------------------------------
__global__ __launch_bounds__(256) void gemm_proj(
    const u16* __restrict__ AH, const u16* __restrict__ BH,
    const float* __restrict__ bias, float* __restrict__ C)
{
    const int N = 1024, K = 1024;
    __shared__ __align__(16) u16 AhT[64 * 32];
    __shared__ __align__(16) u16 BhT[128 * 32];
    const int t = threadIdx.x;
    const int bm = blockIdx.y * 64, bn = blockIdx.x * 128;
    const int wave = t >> 6, lane = t & 63;
    const int l15 = lane & 15, quad = lane >> 4;
    const int srow = lane >> 2;
    const int scol = (((lane & 3) ^ ((lane >> 3) & 3))) * 8;
    const int rq = (quad ^ ((l15 >> 1) & 3)) * 8;

    f32x4 acc[4][2];
    const f32x4 zero = {0.0f, 0.0f, 0.0f, 0.0f};
    #pragma unroll
    for (int i = 0; i < 4; ++i)
        #pragma unroll
        for (int j = 0; j < 2; ++j) acc[i][j] = zero;

    for (int k0 = 0; k0 < K; k0 += 32) {
        {
            const int r0 = wave * 16;
            async16(&AH[(size_t)(bm + r0 + srow) * K + k0 + scol],
                    &AhT[r0 * 32]);
        }
        #pragma unroll
        for (int cc = 0; cc < 2; ++cc) {
            const int r0 = (wave * 2 + cc) * 16;
            async16(&BH[(size_t)(bn + r0 + srow) * K + k0 + scol],
                    &BhT[r0 * 32]);
        }
        __syncthreads();
        bf16x8 ah[4], bh[2];
        #pragma unroll
        for (int i = 0; i < 4; ++i)
            ah[i] = *(const bf16x8*)&AhT[(i * 16 + l15) * 32 + rq];
        #pragma unroll
        for (int j = 0; j < 2; ++j)
            bh[j] = *(const bf16x8*)
                &BhT[(wave * 32 + j * 16 + l15) * 32 + rq];
        #pragma unroll
        for (int i = 0; i < 4; ++i)
            #pragma unroll
            for (int j = 0; j < 2; ++j)
                acc[i][j] = __builtin_amdgcn_mfma_f32_16x16x32_bf16(
                    ah[i], bh[j], acc[i][j], 0, 0, 0);
        __syncthreads();
    }

    #pragma unroll
    for (int j = 0; j < 2; ++j) {
        const int col = bn + wave * 32 + j * 16 + l15;
        const float bv = bias[col];
        #pragma unroll
        for (int i = 0; i < 4; ++i) {
            const int row = bm + i * 16 + quad * 4;
            #pragma unroll
            for (int r = 0; r < 4; ++r)
                C[(size_t)(row + r) * N + col] = acc[i][j][r] + bv;
        }
    }
}

// ---------------------------------------------------------------------------
// MFMA flash attention v12 = v8 geometry (best measured: 4 waves, 128-row
// Q-tile, grid 512, KVBLK=64) + R2's in-reg P + ones-MFMA row-sum.
// R3/R4 refuted: tile-shrink for occupancy (v9/v10) and KVBLK=128 (v11)
// all neutral-to-worse; v8 geometry is the measured optimum of this family.
// UNCHANGED from R5 (clean attribution for the qkv change this round).
// ---------------------------------------------------------------------------
__global__ __launch_bounds__(256) void flash_attn_mfma(
    const u16* __restrict__ Qb, const u16* __restrict__ Kb,
    const u16* __restrict__ Vt, u16* __restrict__ Attn)
{
    __shared__ __align__(16) u16 Klds[2 * 64 * 64];  // swizzled [key][d], dbuf
    __shared__ __align__(16) u16 Vlds[2 * 64 * 64];  // swizzled [d][slot], dbuf

    const int t = threadIdx.x;
    const int bid = blockIdx.x;
    const int bh = bid & 31;       // low bits -> same XCD for all qt of a head
    const int qt = bid >> 5;       // 0..15
    const int n0 = qt * 128;
    const size_t kbase = (size_t)bh * 2048 * 64;
    const size_t vbase = (size_t)bh * 64 * 2048;
    const int wave = t >> 6, lane = t & 63;
    const int l15 = lane & 15, quad = lane >> 4;
    const int srow8 = lane >> 3;
    const int sgrp = lane & 7;

    // Q frags direct from global (B-operand: col=q, k=d); loaded once.
    bf16x8 qf[2][2];
    #pragma unroll
    for (int qs = 0; qs < 2; ++qs) {
        const size_t qrow =
            ((size_t)bh * 2048 + n0 + wave * 32 + qs * 16 + l15) * 64;
        qf[qs][0] = *(const bf16x8*)&Qb[qrow + quad * 8];
        qf[qs][1] = *(const bf16x8*)&Qb[qrow + 32 + quad * 8];
    }

    int kofs[4][2];
    #pragma unroll
    for (int nt = 0; nt < 4; ++nt) {
        const int row = nt * 16 + l15;
        kofs[nt][0] = row * 64 + ((quad ^ (row & 7)) * 8);
        kofs[nt][1] = row * 64 + (((quad + 4) ^ (row & 7)) * 8);
    }

    f32x4 o[2][4];
    const f32x4 zero = {0.0f, 0.0f, 0.0f, 0.0f};
    #pragma unroll
    for (int qs = 0; qs < 2; ++qs)
        #pragma unroll
        for (int dt = 0; dt < 4; ++dt) o[qs][dt] = zero;
    f32x4 osum[2] = {zero, zero};
    bf16x8 ones;
    #pragma unroll
    for (int e = 0; e < 8; ++e) ones[e] = (__bf16)1.0f;

    // prologue: stage K/V tile 0 into buffer 0
    #pragma unroll
    for (int cc = 0; cc < 2; ++cc) {
        const int r0 = (wave + cc * 4) * 8;
        const int row = r0 + srow8;
        const int gg = sgrp ^ (row & 7);
        async16(&Kb[kbase + (size_t)row * 64 + gg * 8], &Klds[r0 * 64]);
        async16(&Vt[vbase + (size_t)row * 2048 + gg * 8], &Vlds[r0 * 64]);
    }

    for (int kt = 0; kt < 32; ++kt) {
        // Single barrier: drains the DMA for buf[kt&1] (issued one full
        // iteration ago) and fences prior-iter reads of buf[(kt+1)&1].
        __syncthreads();
        if (kt + 1 < 32) {   // prefetch next tile into the other buffer
            const int nb = ((kt + 1) & 1) * 4096;
            #pragma unroll
            for (int cc = 0; cc < 2; ++cc) {
                const int r0 = (wave + cc * 4) * 8;
                const int row = r0 + srow8;
                const int gg = sgrp ^ (row & 7);
                async16(&Kb[kbase + (size_t)((kt + 1) * 64 + row) * 64 + gg * 8],
                        &Klds[nb + r0 * 64]);
                async16(&Vt[vbase + (size_t)row * 2048 + (kt + 1) * 64 + gg * 8],
                        &Vlds[nb + r0 * 64]);
            }
        }
        const int cb = (kt & 1) * 4096;

        // S^T = K Q^T : lane gets s[qs][nt][r] = S[key=16nt+4quad+r][q=l15]
        f32x4 s[2][4];
        #pragma unroll
        for (int nt = 0; nt < 4; ++nt) {
            bf16x8 kf0 = *(const bf16x8*)&Klds[cb + kofs[nt][0]];
            bf16x8 kf1 = *(const bf16x8*)&Klds[cb + kofs[nt][1]];
            __builtin_amdgcn_s_setprio(1);
            #pragma unroll
            for (int qs = 0; qs < 2; ++qs) {
                s[qs][nt] = __builtin_amdgcn_mfma_f32_16x16x32_bf16(
                    kf0, qf[qs][0], zero, 0, 0, 0);
                s[qs][nt] = __builtin_amdgcn_mfma_f32_16x16x32_bf16(
                    kf1, qf[qs][1], s[qs][nt], 0, 0, 0);
            }
            __builtin_amdgcn_s_setprio(0);
        }

        // p = exp2(s); pack IN-REGISTER into A-fragments.
        // pf[qs][m] slots quad*8+j: j=0..3 <- s[qs][m][j] (key 16m+4q+j),
        // j=4..7 <- s[qs][m+2][j-4] — matches the Vt slot permutation.
        bf16x8 pf[2][2];
        #pragma unroll
        for (int qs = 0; qs < 2; ++qs) {
            #pragma unroll
            for (int m = 0; m < 2; ++m) {
                u16x8 pk;
                #pragma unroll
                for (int r = 0; r < 4; ++r) {
                    pk[r]     = f2bf_rtz(fast_exp2(s[qs][m][r]));
                    pk[4 + r] = f2bf_rtz(fast_exp2(s[qs][m + 2][r]));
                }
                pf[qs][m] = u2b(pk);
            }
        }

        // O += P V : 2 qsub x 4 d-tiles x 2 ksteps; row-sum via ones-MFMA
        #pragma unroll
        for (int dt = 0; dt < 4; ++dt) {
            bf16x8 vf0 = *(const bf16x8*)&Vlds[cb + kofs[dt][0]];
            bf16x8 vf1 = *(const bf16x8*)&Vlds[cb + kofs[dt][1]];
            __builtin_amdgcn_s_setprio(1);
            #pragma unroll
            for (int qs = 0; qs < 2; ++qs) {
                o[qs][dt] = __builtin_amdgcn_mfma_f32_16x16x32_bf16(
                    pf[qs][0], vf0, o[qs][dt], 0, 0, 0);
                o[qs][dt] = __builtin_amdgcn_mfma_f32_16x16x32_bf16(
                    pf[qs][1], vf1, o[qs][dt], 0, 0, 0);
            }
            __builtin_amdgcn_s_setprio(0);
        }
        __builtin_amdgcn_s_setprio(1);
        #pragma unroll
        for (int qs = 0; qs < 2; ++qs) {
            osum[qs] = __builtin_amdgcn_mfma_f32_16x16x32_bf16(
                pf[qs][0], ones, osum[qs], 0, 0, 0);
            osum[qs] = __builtin_amdgcn_mfma_f32_16x16x32_bf16(
                pf[qs][1], ones, osum[qs], 0, 0, 0);
        }
        __builtin_amdgcn_s_setprio(0);
    }

    // osum[qs][r] on lane(l15,quad) = sum_k P[q=quad*4+r][k], replicated
    // over l15 — exactly the epilogue row indexing. No shfl/LDS needed.
    const size_t obase =
        ((size_t)(bh >> 4) * 2048 + n0) * 1024 + (bh & 15) * 64;
    #pragma unroll
    for (int qs = 0; qs < 2; ++qs)
        #pragma unroll
        for (int r = 0; r < 4; ++r) {
            const float inv = 1.0f / osum[qs][r];
            const size_t rbase =
                obase + (size_t)(wave * 32 + qs * 16 + quad * 4 + r) * 1024;
            #pragma unroll
            for (int dt = 0; dt < 4; ++dt)
                Attn[rbase + dt * 16 + l15] = f2bf(o[qs][dt][r] * inv);
        }
}

// ---------------------------------------------------------------------------
extern "C" void kernel_launch(void* const* d_in, const int* in_sizes, int n_in,
                              void* d_out, int out_size, void* d_ws, size_t ws_size,
                              hipStream_t stream)
{
    const float* x      = (const float*)d_in[0];  // [2,2048,1024] f32
    const float* qkv_w  = (const float*)d_in[1];  // [1024,3072]
    const float* qkv_b  = (const float*)d_in[2];  // [3072]
    const float* q_nw   = (const float*)d_in[3];  // [64]
    const float* k_nw   = (const float*)d_in[4];  // [64]
    const float* proj_w = (const float*)d_in[5];  // [1024,1024]
    const float* proj_b = (const float*)d_in[6];  // [1024]
    float* out = (float*)d_out;                   // [2,2048,1024] f32

    // ws layout (48 MB):
    //  [0,8M)    Attn bf16
    //  [8,14M)   qwT bf16     [14,16M) pwT bf16
    //  [16,24M)  Xb bf16
    //  [24,32M)  Qb bf16      [32,40M) Kb bf16   [40,48M) Vt bf16
    char* ws = (char*)d_ws;
    u16* AttnB = (u16*)ws;
    u16* qwT   = (u16*)(ws + 8388608);
    u16* pwT   = (u16*)(ws + 14680064);
    u16* Xb    = (u16*)(ws + 16777216);
    u16* QbB   = (u16*)(ws + 25165824);
    u16* KbB   = (u16*)(ws + 33554432);
    u16* VtB   = (u16*)(ws + 41943040);
    (void)in_sizes; (void)n_in; (void)out_size;
    // Diagnostic guard: if ws too small, emit nothing -> absmax == max|ref|.
    if (ws_size < 50331648u) return;

    // merged prepass: cast x + transpose both weights (one launch)
    prep<<<dim3(6144), 256, 0, stream>>>(x, Xb, qkv_w, qwT, proj_w, pwT);
    // QKV GEMM: BK=64, chunk-XOR swizzle, XCD-chunked 1-D grid (768 blocks)
    gemm_qkv<<<dim3(768), 256, 0, stream>>>(
        Xb, qwT, qkv_b, QbB, KbB, VtB, q_nw, k_nw);
    // flash attention v12 (v8 geometry + in-reg P + osum) — unchanged
    flash_attn_mfma<<<dim3(512), 256, 0, stream>>>(QbB, KbB, VtB, AttnB);
    // out = attn @ proj_w + proj_b (f32), R1 staging + LDS swizzle
    gemm_proj<<<dim3(1024 / 128, 4096 / 64), 256, 0, stream>>>(
        AttnB, pwT, proj_b, out);
}

// Round 7
// 190.846 us; speedup vs baseline: 1.0681x; 1.0385x over previous
//
#include <hip/hip_runtime.h>

typedef unsigned short u16;
typedef unsigned int u32;
typedef __bf16 bf16x8 __attribute__((ext_vector_type(8)));
typedef float f32x4 __attribute__((ext_vector_type(4)));
typedef unsigned short u16x8 __attribute__((ext_vector_type(8)));
typedef unsigned short u16x4 __attribute__((ext_vector_type(4)));

__device__ __forceinline__ float bf2f(u16 u) {
    union { unsigned int i; float f; } c; c.i = ((unsigned int)u) << 16; return c.f;
}
__device__ __forceinline__ u16 f2bf(float f) {
    union { float f; unsigned int i; } c; c.f = f;
    unsigned int r = c.i + 0x7FFFu + ((c.i >> 16) & 1u);  // RNE
    return (u16)(r >> 16);
}
__device__ __forceinline__ u16 f2bf_rtz(float f) {   // truncate: 1 VALU op
    union { float f; unsigned int i; } c; c.f = f;
    return (u16)(c.i >> 16);
}
__device__ __forceinline__ float fast_exp2(float x) {
#if __has_builtin(__builtin_amdgcn_exp2f)
    return __builtin_amdgcn_exp2f(x);   // raw v_exp_f32, no OCML fixup
#else
    return exp2f(x);
#endif
}
__device__ __forceinline__ bf16x8 u2b(u16x8 v) {
    return __builtin_bit_cast(bf16x8, v);
}
// async global->LDS, 16B/lane; LDS dest = wave-uniform base + lane*16
__device__ __forceinline__ void async16(const void* g, void* l) {
    __builtin_amdgcn_global_load_lds(
        (const __attribute__((address_space(1))) u32*)g,
        (__attribute__((address_space(3))) u32*)l, 16, 0, 0);
}

// ---------------------------------------------------------------------------
// Merged prepass (one launch) — measured win (R11/R12):
//  blocks [0,2048):    x f32 -> bf16 Xb (8 elems/thread)
//  blocks [2048,5120): transpose+cast qkv_w [1024][3072] -> qwT [3072][1024]
//  blocks [5120,6144): transpose+cast proj_w [1024][1024] -> pwT [1024][1024]
// ---------------------------------------------------------------------------
__global__ __launch_bounds__(256) void prep(
    const float* __restrict__ X, u16* __restrict__ Xb,
    const float* __restrict__ qkv_w, u16* __restrict__ qwT,
    const float* __restrict__ proj_w, u16* __restrict__ pwT)
{
    __shared__ float tile[32][33];
    const int blk = blockIdx.x;
    const int t = threadIdx.x;
    if (blk < 2048) {
        const size_t i = ((size_t)blk * 256 + t) * 8;
        u16x8 h;
        #pragma unroll
        for (int e = 0; e < 8; ++e) h[e] = f2bf(X[i + e]);
        *(u16x8*)&Xb[i] = h;
        return;
    }
    const float* W; u16* Th; int K, N, bx, by;
    if (blk < 5120) {
        W = qkv_w; Th = qwT; K = 1024; N = 3072;
        bx = (blk - 2048) % 96; by = (blk - 2048) / 96;
    } else {
        W = proj_w; Th = pwT; K = 1024; N = 1024;
        bx = (blk - 5120) % 32; by = (blk - 5120) / 32;
    }
    const int bk = by * 32, bn = bx * 32;
    const int tx = t & 31, ty = t >> 5;  // 32 x 8
    #pragma unroll
    for (int r = ty; r < 32; r += 8)
        tile[r][tx] = W[(size_t)(bk + r) * N + bn + tx];
    __syncthreads();
    #pragma unroll
    for (int r = ty; r < 32; r += 8)
        Th[(size_t)(bn + r) * K + bk + tx] = f2bf(tile[tx][r]);
}

// ---------------------------------------------------------------------------
// QKV GEMM — exact R5 version (best measured): 128x128 tile, BK=32, R1
// two-barrier staging, LDS XOR-swizzle (conflicts 0, verified R5/R6).
// R6's BK=64 + XCD-chunked grid reverted: profiled regression, FETCH
// unchanged, clean total neutral.
// Fused bias + per-head RMSNorm -> Qb/Kb bf16 [bh][n][64] (q gets
// 1/8*log2e folded), V transpose -> Vt [bh][d][n] with key-slot perm.
// C/D layout: col = lane&15, row = (lane>>4)*4 + reg (verified m89/m91).
// ---------------------------------------------------------------------------
__global__ __launch_bounds__(256) void gemm_qkv(
    const u16* __restrict__ AH, const u16* __restrict__ BH,
    const float* __restrict__ bias,
    u16* __restrict__ Qb, u16* __restrict__ Kb, u16* __restrict__ Vt,
    const float* __restrict__ qw, const float* __restrict__ kw)
{
    const int K = 1024;
    __shared__ __align__(16) u16 AhT[128 * 32];
    __shared__ __align__(16) u16 BhT[128 * 32];
    const int t = threadIdx.x;
    const int bm = blockIdx.y * 128, bn = blockIdx.x * 128;
    const int wave = t >> 6, lane = t & 63;
    const int wm = (wave >> 1) * 64, wn = (wave & 1) * 64;
    const int l15 = lane & 15, quad = lane >> 4;
    // staging: 16B/lane; row = r0 + (lane>>2); global col chunk carries the
    // inverse swizzle g(row) = (row>>1)&3 = (lane>>3)&3  (r0 multiple of 16)
    const int srow = lane >> 2;
    const int scol = (((lane & 3) ^ ((lane >> 3) & 3))) * 8;
    // fragment-read swizzle: slot = quad ^ ((row>>1)&3), row = ..16*i + l15
    const int rq = (quad ^ ((l15 >> 1) & 3)) * 8;

    f32x4 acc[4][4];
    const f32x4 zero = {0.0f, 0.0f, 0.0f, 0.0f};
    #pragma unroll
    for (int i = 0; i < 4; ++i)
        #pragma unroll
        for (int j = 0; j < 4; ++j) acc[i][j] = zero;

    for (int k0 = 0; k0 < K; k0 += 32) {
        #pragma unroll
        for (int rr = 0; rr < 2; ++rr) {
            const int r0 = (rr * 4 + wave) * 16;
            const size_t ga = (size_t)(bm + r0 + srow) * K + k0 + scol;
            const size_t gb = (size_t)(bn + r0 + srow) * K + k0 + scol;
            async16(&AH[ga], &AhT[r0 * 32]);
            async16(&BH[gb], &BhT[r0 * 32]);
        }
        __syncthreads();
        bf16x8 ah[4], bh[4];
        #pragma unroll
        for (int i = 0; i < 4; ++i)
            ah[i] = *(const bf16x8*)&AhT[(wm + i * 16 + l15) * 32 + rq];
        #pragma unroll
        for (int j = 0; j < 4; ++j)
            bh[j] = *(const bf16x8*)&BhT[(wn + j * 16 + l15) * 32 + rq];
        #pragma unroll
        for (int i = 0; i < 4; ++i)
            #pragma unroll
            for (int j = 0; j < 4; ++j)
                acc[i][j] = __builtin_amdgcn_mfma_f32_16x16x32_bf16(
                    ah[i], bh[j], acc[i][j], 0, 0, 0);
        __syncthreads();
    }

    // wave's 64-col group = one (section, head) pair
    const int gc0 = bn + wn;
    const int sec = gc0 >> 10;              // 0=q, 1=k, 2=v
    const int h = (gc0 & 1023) >> 6;
    const int b = bm >> 11;
    const int bhd = b * 16 + h;
    float bv[4], wj[4];
    #pragma unroll
    for (int j = 0; j < 4; ++j) {
        const int d = j * 16 + l15;
        bv[j] = bias[gc0 + d];
        wj[j] = (sec == 2) ? 0.0f : (sec ? kw[d] : qw[d] * 0.18033688011f);
    }
    if (sec < 2) {
        u16* dst = sec ? Kb : Qb;
        #pragma unroll
        for (int i = 0; i < 4; ++i) {
            float val[4][4];
            float ss[4] = {0.0f, 0.0f, 0.0f, 0.0f};
            #pragma unroll
            for (int j = 0; j < 4; ++j)
                #pragma unroll
                for (int r = 0; r < 4; ++r) {
                    val[j][r] = acc[i][j][r] + bv[j];
                    ss[r] += val[j][r] * val[j][r];
                }
            #pragma unroll
            for (int r = 0; r < 4; ++r) {
                #pragma unroll
                for (int m = 1; m < 16; m <<= 1)
                    ss[r] += __shfl_xor(ss[r], m, 64);
                const float nrm = rsqrtf(ss[r] * 0.015625f + 1e-6f);
                const int n = (bm + wm + i * 16 + quad * 4 + r) & 2047;
                const size_t rowb = ((size_t)bhd * 2048 + n) * 64;
                #pragma unroll
                for (int j = 0; j < 4; ++j)
                    dst[rowb + j * 16 + l15] = f2bf(val[j][r] * nrm * wj[j]);
            }
        }
    } else {
        const int nb = (bm + wm) & 2047;        // 64-aligned tile base
        #pragma unroll
        for (int i = 0; i < 4; ++i) {
            // slot permutation: key 16*i+4*quad+r -> (i&1)*32+8*quad+(i>>1)*4+r
            const int s0 = (i & 1) * 32 + quad * 8 + (i >> 1) * 4;
            #pragma unroll
            for (int j = 0; j < 4; ++j) {
                const int d = j * 16 + l15;
                u16x4 pk;
                #pragma unroll
                for (int r = 0; r < 4; ++r)
                    pk[r] = f2bf(acc[i][j][r] + bv[j]);
                *(u16x4*)&Vt[((size_t)bhd * 64 + d) * 2048 + nb + s0] = pk;
            }
        }
    }
}

// ---------------------------------------------------------------------------
// Proj GEMM — R7: 64x128 tile, TWO BK=32 sub-tiles per barrier pair
// (16 intervals of 16 MFMA/wave instead of 32 of 8). Proj had the worst
// compute-per-barrier ratio of the three MFMA kernels; this halves the
// barrier/drain count while keeping the proven R5 per-sub-tile layout,
// swizzle, and fragment code verbatim. LDS 12 -> 24 KB (still >=2 blk/CU).
// out f32 = Attn @ pwT^T + bias.
// ---------------------------------------------------------------------------
__global__ __launch_bounds__(256) void gemm_proj(
    const u16* __restrict__ AH, const u16* __restrict__ BH,
    const float* __restrict__ bias, float* __restrict__ C)
{
    const int N = 1024, K = 1024;
    __shared__ __align__(16) u16 AhT[2 * 64 * 32];
    __shared__ __align__(16) u16 BhT[2 * 128 * 32];
    const int t = threadIdx.x;
    const int bm = blockIdx.y * 64, bn = blockIdx.x * 128;
    const int wave = t >> 6, lane = t & 63;
    const int l15 = lane & 15, quad = lane >> 4;
    const int srow = lane >> 2;
    const int scol = (((lane & 3) ^ ((lane >> 3) & 3))) * 8;
    const int rq = (quad ^ ((l15 >> 1) & 3)) * 8;

    f32x4 acc[4][2];
    const f32x4 zero = {0.0f, 0.0f, 0.0f, 0.0f};
    #pragma unroll
    for (int i = 0; i < 4; ++i)
        #pragma unroll
        for (int j = 0; j < 2; ++j) acc[i][j] = zero;

    for (int k0 = 0; k0 < K; k0 += 64) {
        #pragma unroll
        for (int s = 0; s < 2; ++s) {
            const int kk = k0 + s * 32;
            {
                const int r0 = wave * 16;
                async16(&AH[(size_t)(bm + r0 + srow) * K + kk + scol],
                        &AhT[s * 2048 + r0 * 32]);
            }
            #pragma unroll
            for (int cc = 0; cc < 2; ++cc) {
                const int r0 = (wave * 2 + cc) * 16;
                async16(&BH[(size_t)(bn + r0 + srow) * K + kk + scol],
                        &BhT[s * 4096 + r0 * 32]);
            }
        }
        __syncthreads();
        #pragma unroll
        for (int s = 0; s < 2; ++s) {
            const int ab = s * 2048, bb = s * 4096;
            bf16x8 ah[4], bh[2];
            #pragma unroll
            for (int i = 0; i < 4; ++i)
                ah[i] = *(const bf16x8*)&AhT[ab + (i * 16 + l15) * 32 + rq];
            #pragma unroll
            for (int j = 0; j < 2; ++j)
                bh[j] = *(const bf16x8*)
                    &BhT[bb + (wave * 32 + j * 16 + l15) * 32 + rq];
            #pragma unroll
            for (int i = 0; i < 4; ++i)
                #pragma unroll
                for (int j = 0; j < 2; ++j)
                    acc[i][j] = __builtin_amdgcn_mfma_f32_16x16x32_bf16(
                        ah[i], bh[j], acc[i][j], 0, 0, 0);
        }
        __syncthreads();
    }

    #pragma unroll
    for (int j = 0; j < 2; ++j) {
        const int col = bn + wave * 32 + j * 16 + l15;
        const float bv = bias[col];
        #pragma unroll
        for (int i = 0; i < 4; ++i) {
            const int row = bm + i * 16 + quad * 4;
            #pragma unroll
            for (int r = 0; r < 4; ++r)
                C[(size_t)(row + r) * N + col] = acc[i][j][r] + bv;
        }
    }
}

// ---------------------------------------------------------------------------
// MFMA flash attention v13 = v12 minus all s_setprio (m190: setprio hurts
// barrier-synced multi-wave kernels; our 4-wave lockstep matches that case,
// and the 14 toggle pairs/iter burn issue slots in a 78%-issue-bound body).
// v8 geometry (4 waves, 128-row Q-tile, grid 512, KVBLK=64) + in-reg P +
// ones-MFMA row-sum — all verified.
// Grid 1-D 512; bh = bid & 31 keeps a head's 16 q-tiles on one XCD.
// ---------------------------------------------------------------------------
__global__ __launch_bounds__(256) void flash_attn_mfma(
    const u16* __restrict__ Qb, const u16* __restrict__ Kb,
    const u16* __restrict__ Vt, u16* __restrict__ Attn)
{
    __shared__ __align__(16) u16 Klds[2 * 64 * 64];  // swizzled [key][d], dbuf
    __shared__ __align__(16) u16 Vlds[2 * 64 * 64];  // swizzled [d][slot], dbuf

    const int t = threadIdx.x;
    const int bid = blockIdx.x;
    const int bh = bid & 31;       // low bits -> same XCD for all qt of a head
    const int qt = bid >> 5;       // 0..15
    const int n0 = qt * 128;
    const size_t kbase = (size_t)bh * 2048 * 64;
    const size_t vbase = (size_t)bh * 64 * 2048;
    const int wave = t >> 6, lane = t & 63;
    const int l15 = lane & 15, quad = lane >> 4;
    const int srow8 = lane >> 3;
    const int sgrp = lane & 7;

    // Q frags direct from global (B-operand: col=q, k=d); loaded once.
    bf16x8 qf[2][2];
    #pragma unroll
    for (int qs = 0; qs < 2; ++qs) {
        const size_t qrow =
            ((size_t)bh * 2048 + n0 + wave * 32 + qs * 16 + l15) * 64;
        qf[qs][0] = *(const bf16x8*)&Qb[qrow + quad * 8];
        qf[qs][1] = *(const bf16x8*)&Qb[qrow + 32 + quad * 8];
    }

    int kofs[4][2];
    #pragma unroll
    for (int nt = 0; nt < 4; ++nt) {
        const int row = nt * 16 + l15;
        kofs[nt][0] = row * 64 + ((quad ^ (row & 7)) * 8);
        kofs[nt][1] = row * 64 + (((quad + 4) ^ (row & 7)) * 8);
    }

    f32x4 o[2][4];
    const f32x4 zero = {0.0f, 0.0f, 0.0f, 0.0f};
    #pragma unroll
    for (int qs = 0; qs < 2; ++qs)
        #pragma unroll
        for (int dt = 0; dt < 4; ++dt) o[qs][dt] = zero;
    f32x4 osum[2] = {zero, zero};
    bf16x8 ones;
    #pragma unroll
    for (int e = 0; e < 8; ++e) ones[e] = (__bf16)1.0f;

    // prologue: stage K/V tile 0 into buffer 0
    #pragma unroll
    for (int cc = 0; cc < 2; ++cc) {
        const int r0 = (wave + cc * 4) * 8;
        const int row = r0 + srow8;
        const int gg = sgrp ^ (row & 7);
        async16(&Kb[kbase + (size_t)row * 64 + gg * 8], &Klds[r0 * 64]);
        async16(&Vt[vbase + (size_t)row * 2048 + gg * 8], &Vlds[r0 * 64]);
    }

    for (int kt = 0; kt < 32; ++kt) {
        // Single barrier: drains the DMA for buf[kt&1] (issued one full
        // iteration ago) and fences prior-iter reads of buf[(kt+1)&1].
        __syncthreads();
        if (kt + 1 < 32) {   // prefetch next tile into the other buffer
            const int nb = ((kt + 1) & 1) * 4096;
            #pragma unroll
            for (int cc = 0; cc < 2; ++cc) {
                const int r0 = (wave + cc * 4) * 8;
                const int row = r0 + srow8;
                const int gg = sgrp ^ (row & 7);
                async16(&Kb[kbase + (size_t)((kt + 1) * 64 + row) * 64 + gg * 8],
                        &Klds[nb + r0 * 64]);
                async16(&Vt[vbase + (size_t)row * 2048 + (kt + 1) * 64 + gg * 8],
                        &Vlds[nb + r0 * 64]);
            }
        }
        const int cb = (kt & 1) * 4096;

        // S^T = K Q^T : lane gets s[qs][nt][r] = S[key=16nt+4quad+r][q=l15]
        f32x4 s[2][4];
        #pragma unroll
        for (int nt = 0; nt < 4; ++nt) {
            bf16x8 kf0 = *(const bf16x8*)&Klds[cb + kofs[nt][0]];
            bf16x8 kf1 = *(const bf16x8*)&Klds[cb + kofs[nt][1]];
            #pragma unroll
            for (int qs = 0; qs < 2; ++qs) {
                s[qs][nt] = __builtin_amdgcn_mfma_f32_16x16x32_bf16(
                    kf0, qf[qs][0], zero, 0, 0, 0);
                s[qs][nt] = __builtin_amdgcn_mfma_f32_16x16x32_bf16(
                    kf1, qf[qs][1], s[qs][nt], 0, 0, 0);
            }
        }

        // p = exp2(s); pack IN-REGISTER into A-fragments.
        // pf[qs][m] slots quad*8+j: j=0..3 <- s[qs][m][j] (key 16m+4q+j),
        // j=4..7 <- s[qs][m+2][j-4] — matches the Vt slot permutation.
        bf16x8 pf[2][2];
        #pragma unroll
        for (int qs = 0; qs < 2; ++qs) {
            #pragma unroll
            for (int m = 0; m < 2; ++m) {
                u16x8 pk;
                #pragma unroll
                for (int r = 0; r < 4; ++r) {
                    pk[r]     = f2bf_rtz(fast_exp2(s[qs][m][r]));
                    pk[4 + r] = f2bf_rtz(fast_exp2(s[qs][m + 2][r]));
                }
                pf[qs][m] = u2b(pk);
            }
        }

        // O += P V : 2 qsub x 4 d-tiles x 2 ksteps; row-sum via ones-MFMA
        #pragma unroll
        for (int dt = 0; dt < 4; ++dt) {
            bf16x8 vf0 = *(const bf16x8*)&Vlds[cb + kofs[dt][0]];
            bf16x8 vf1 = *(const bf16x8*)&Vlds[cb + kofs[dt][1]];
            #pragma unroll
            for (int qs = 0; qs < 2; ++qs) {
                o[qs][dt] = __builtin_amdgcn_mfma_f32_16x16x32_bf16(
                    pf[qs][0], vf0, o[qs][dt], 0, 0, 0);
                o[qs][dt] = __builtin_amdgcn_mfma_f32_16x16x32_bf16(
                    pf[qs][1], vf1, o[qs][dt], 0, 0, 0);
            }
        }
        #pragma unroll
        for (int qs = 0; qs < 2; ++qs) {
            osum[qs] = __builtin_amdgcn_mfma_f32_16x16x32_bf16(
                pf[qs][0], ones, osum[qs], 0, 0, 0);
            osum[qs] = __builtin_amdgcn_mfma_f32_16x16x32_bf16(
                pf[qs][1], ones, osum[qs], 0, 0, 0);
        }
    }

    // osum[qs][r] on lane(l15,quad) = sum_k P[q=quad*4+r][k], replicated
    // over l15 — exactly the epilogue row indexing. No shfl/LDS needed.
    const size_t obase =
        ((size_t)(bh >> 4) * 2048 + n0) * 1024 + (bh & 15) * 64;
    #pragma unroll
    for (int qs = 0; qs < 2; ++qs)
        #pragma unroll
        for (int r = 0; r < 4; ++r) {
            const float inv = 1.0f / osum[qs][r];
            const size_t rbase =
                obase + (size_t)(wave * 32 + qs * 16 + quad * 4 + r) * 1024;
            #pragma unroll
            for (int dt = 0; dt < 4; ++dt)
                Attn[rbase + dt * 16 + l15] = f2bf(o[qs][dt][r] * inv);
        }
}

// ---------------------------------------------------------------------------
extern "C" void kernel_launch(void* const* d_in, const int* in_sizes, int n_in,
                              void* d_out, int out_size, void* d_ws, size_t ws_size,
                              hipStream_t stream)
{
    const float* x      = (const float*)d_in[0];  // [2,2048,1024] f32
    const float* qkv_w  = (const float*)d_in[1];  // [1024,3072]
    const float* qkv_b  = (const float*)d_in[2];  // [3072]
    const float* q_nw   = (const float*)d_in[3];  // [64]
    const float* k_nw   = (const float*)d_in[4];  // [64]
    const float* proj_w = (const float*)d_in[5];  // [1024,1024]
    const float* proj_b = (const float*)d_in[6];  // [1024]
    float* out = (float*)d_out;                   // [2,2048,1024] f32

    // ws layout (48 MB):
    //  [0,8M)    Attn bf16
    //  [8,14M)   qwT bf16     [14,16M) pwT bf16
    //  [16,24M)  Xb bf16
    //  [24,32M)  Qb bf16      [32,40M) Kb bf16   [40,48M) Vt bf16
    char* ws = (char*)d_ws;
    u16* AttnB = (u16*)ws;
    u16* qwT   = (u16*)(ws + 8388608);
    u16* pwT   = (u16*)(ws + 14680064);
    u16* Xb    = (u16*)(ws + 16777216);
    u16* QbB   = (u16*)(ws + 25165824);
    u16* KbB   = (u16*)(ws + 33554432);
    u16* VtB   = (u16*)(ws + 41943040);
    (void)in_sizes; (void)n_in; (void)out_size;
    // Diagnostic guard: if ws too small, emit nothing -> absmax == max|ref|.
    if (ws_size < 50331648u) return;

    // merged prepass: cast x + transpose both weights (one launch)
    prep<<<dim3(6144), 256, 0, stream>>>(x, Xb, qkv_w, qwT, proj_w, pwT);
    // QKV GEMM (R5 exact: BK=32, swizzle) + fused bias/RMSNorm epilogue
    gemm_qkv<<<dim3(3072 / 128, 4096 / 128), 256, 0, stream>>>(
        Xb, qwT, qkv_b, QbB, KbB, VtB, q_nw, k_nw);
    // flash attention v13 (v12 minus setprio)
    flash_attn_mfma<<<dim3(512), 256, 0, stream>>>(QbB, KbB, VtB, AttnB);
    // out = attn @ proj_w + proj_b (f32): 2 sub-tiles per barrier pair
    gemm_proj<<<dim3(1024 / 128, 4096 / 64), 256, 0, stream>>>(
        AttnB, pwT, proj_b, out);
}